// Round 1
// 498.620 us; speedup vs baseline: 1.2507x; 1.2507x over previous
//
#include <hip/hip_runtime.h>

#define F 3
#define V 512
#define D 8192
#define B 64
#define ITERS 10
#define DW 256  // u32 words per D-row (D/32)

typedef __bf16 bf16_t;
typedef __bf16 bf16x8 __attribute__((ext_vector_type(8)));
typedef float f32x4 __attribute__((ext_vector_type(4)));
typedef unsigned int u32;
typedef unsigned long long u64;

// ---------------------------------------------------------------------------
// All values in this problem are in {0, +1, -1}. Bit encoding:
//   sign bit s = 1  <=> value < 0
//   zero bit z = 1  <=> value == 0   (sign bit is canonically 0 when zero)
// Product of +-1 values: sign = XOR of sign bits. Zero if any zero: OR of z.
// dot(A, c) with A in {0,+-1}, c in {+-1}:
//   = nzc - 2*popc((As ^ cs) & ~Az_or)   where nzc = popc(~Az_or)
// has_zero flag: once any est zero is ever produced, all later k_sim calls
// take the masked slow path (conservative, exact).
// inputs and init_estimates are +-1 by problem construction (jnp.where(..==0,1)).
// ---------------------------------------------------------------------------

// ---------------------------------------------------------------------------
// init (transpose + codebook bit-pack): CbT[f][d][v] = bf16(codebooks[f][v][d])
// and Cbits[f][wc][v][j] = sign bits of codebooks[f][v][32*(4*wc+j) .. +32)
// (uint4-tiled so k_sim lane v reads 16B coalesced per 4-word chunk)
// ---------------------------------------------------------------------------
__global__ __launch_bounds__(256) void k_init_tr(const float* __restrict__ Csrc,
                                                 bf16_t* __restrict__ CbT,
                                                 u32* __restrict__ Cbits) {
  int f = blockIdx.z, vt = blockIdx.y, dt = blockIdx.x;
  __shared__ bf16_t tile[64 * 65];
  int t = threadIdx.x;
  int lane = t & 63;
  int v0 = vt * 64, d0 = dt * 64;
#pragma unroll
  for (int p = 0; p < 16; ++p) {
    int q = t + 256 * p;
    int i = q >> 6, j = q & 63;  // j == lane, i uniform per wave
    float x = Csrc[((long)(f * V + v0 + i)) * D + d0 + j];
    tile[i * 65 + j] = (bf16_t)x;
    u64 bal = __ballot(x < 0.f);  // bit l <-> d = d0 + l
    if (lane == 0) {
      int v = v0 + i;
      // words w0 = dt*2 (+0,+1); uint4 chunk wc = dt>>1, slots 2*(dt&1), +1
      uint2 wp;
      wp.x = (u32)(bal & 0xffffffffull);
      wp.y = (u32)(bal >> 32);
      *(uint2*)&Cbits[(((f * 64 + (dt >> 1)) * 512) + v) * 4 + (dt & 1) * 2] = wp;
    }
  }
  __syncthreads();
#pragma unroll
  for (int p = 0; p < 16; ++p) {
    int q = t + 256 * p;
    int jj = q >> 6, ii = q & 63;
    CbT[((long)f * D + d0 + jj) * V + v0 + ii] = tile[ii * 65 + jj];
  }
}

// ---------------------------------------------------------------------------
// init (bit-pack inputs + init estimates, zero the flag block)
// in_bits[b][w], es0/ez0[(b*F+f)][w]
// ---------------------------------------------------------------------------
__global__ void k_init_pack(const float* __restrict__ inputs, const float* __restrict__ ie,
                            u32* __restrict__ in_bits, u32* __restrict__ es0,
                            u32* __restrict__ ez0, int* __restrict__ flags) {
  int tid = blockIdx.x * blockDim.x + threadIdx.x;
  int lane = tid & 63;
  int gw = tid >> 6;
  int NW = (gridDim.x * blockDim.x) >> 6;
  const int IN_W = B * (D / 64);       // 8192 64-elem chunks
  const int EST_W = B * F * (D / 64);  // 24576
  for (int c = gw; c < IN_W + EST_W; c += NW) {
    if (c < IN_W) {
      int b = c >> 7, dc = c & 127;
      float x = inputs[(long)b * D + dc * 64 + lane];
      u64 bal = __ballot(x < 0.f);
      if (lane == 0) {
        in_bits[b * DW + dc * 2] = (u32)(bal & 0xffffffffull);
        in_bits[b * DW + dc * 2 + 1] = (u32)(bal >> 32);
      }
    } else {
      int cc = c - IN_W;
      int bf = cc >> 7, dc = cc & 127;  // bf = b*F + f (ie is [b][f][d])
      float x = ie[(long)bf * D + dc * 64 + lane];
      u64 bs = __ballot(x < 0.f);
      u64 bz = __ballot(x == 0.f);  // all-zero by construction, stored for safety
      if (lane == 0) {
        es0[bf * DW + dc * 2] = (u32)(bs & 0xffffffffull);
        es0[bf * DW + dc * 2 + 1] = (u32)(bs >> 32);
        ez0[bf * DW + dc * 2] = (u32)(bz & 0xffffffffull);
        ez0[bf * DW + dc * 2 + 1] = (u32)(bz >> 32);
      }
    }
  }
  if (tid < 32) flags[tid] = 0;  // anydiff[0..15], has_zero at [16]
}

// ---------------------------------------------------------------------------
// kernel A (binary): sim[f][b][v] = dot over D of A and codebook row v.
//   iter <  ITERS : A = inputs * est_f1 * est_f2   (XOR of sign planes)
//   iter == ITERS : A = est itself                 (final projection)
// One wave per (f, b-pair, 64-v group): 768 waves = 192 blocks x 256.
// A sign-words live in 4 VGPRs/lane; broadcast word-by-word via v_readlane.
// No LDS, no MFMA, no atomics; each sim element written exactly once.
// ---------------------------------------------------------------------------
__global__ __launch_bounds__(256) void k_sim(const u32* __restrict__ Cbits,
                                             const u32* __restrict__ in_bits,
                                             const u32* __restrict__ es0,
                                             const u32* __restrict__ ez0,
                                             const u32* __restrict__ es1,
                                             const u32* __restrict__ ez1,
                                             int* __restrict__ simBase,
                                             const int* __restrict__ anydiff,
                                             const int* __restrict__ hzp, int iter) {
  const int t = threadIdx.x, lane = t & 63;
  const int gw = blockIdx.x * 4 + (t >> 6);  // 0..767
  const int vg = gw & 7, bp = (gw >> 3) & 31, f = gw >> 8;
  const int b0 = bp * 2;
  const bool is_final = (iter >= ITERS);
  const u32 *es, *ez;
  int* sim;
  if (is_final) {
    int first0 = ITERS;
    for (int i = 0; i < ITERS; ++i)
      if (anydiff[i] == 0) { first0 = i; break; }
    int par = (first0 < ITERS) ? ((first0 + 1) & 1) : 0;
    es = par ? es1 : es0;
    ez = par ? ez1 : ez0;
    sim = simBase + ITERS * (F * B * V);
  } else {
    for (int i = 0; i < iter; ++i)
      if (anydiff[i] == 0) return;  // converged earlier: uniform exit
    es = (iter & 1) ? es1 : es0;
    ez = (iter & 1) ? ez1 : ez0;
    sim = simBase + iter * (F * B * V);
  }
  const int hz = *hzp;

  u32 As0[4], As1[4], Az0[4], Az1[4];
  if (is_final) {
    const int i0 = (b0 * F + f) * DW, i1 = ((b0 + 1) * F + f) * DW;
#pragma unroll
    for (int r = 0; r < 4; ++r) {
      int o = r * 64 + lane;
      As0[r] = es[i0 + o];
      As1[r] = es[i1 + o];
    }
    if (hz) {
#pragma unroll
      for (int r = 0; r < 4; ++r) {
        int o = r * 64 + lane;
        Az0[r] = ~ez[i0 + o];
        Az1[r] = ~ez[i1 + o];
      }
    }
  } else {
    const int f1 = (f + 1) % 3, f2 = (f + 2) % 3;
    const int a0 = (b0 * F + f1) * DW, a1 = (b0 * F + f2) * DW;
    const int c0 = ((b0 + 1) * F + f1) * DW, c1 = ((b0 + 1) * F + f2) * DW;
    const int n0 = b0 * DW, n1 = (b0 + 1) * DW;
#pragma unroll
    for (int r = 0; r < 4; ++r) {
      int o = r * 64 + lane;
      As0[r] = in_bits[n0 + o] ^ es[a0 + o] ^ es[a1 + o];
      As1[r] = in_bits[n1 + o] ^ es[c0 + o] ^ es[c1 + o];
    }
    if (hz) {
#pragma unroll
      for (int r = 0; r < 4; ++r) {
        int o = r * 64 + lane;
        Az0[r] = ~(ez[a0 + o] | ez[a1 + o]);
        Az1[r] = ~(ez[c0 + o] | ez[c1 + o]);
      }
    }
  }

  int nzc0 = D, nzc1 = D;
  if (hz) {
    int p0 = 0, p1 = 0;
#pragma unroll
    for (int r = 0; r < 4; ++r) {
      p0 += __popc(Az0[r]);
      p1 += __popc(Az1[r]);
    }
    for (int off = 32; off; off >>= 1) {
      p0 += __shfl_xor(p0, off, 64);
      p1 += __shfl_xor(p1, off, 64);
    }
    nzc0 = p0;
    nzc1 = p1;
  }

  int acc0 = 0, acc1 = 0;
  const uint4* Cp = (const uint4*)Cbits + ((long)f * 64) * 512 + vg * 64 + lane;
  if (!hz) {
#pragma unroll
    for (int r = 0; r < 4; ++r) {
#pragma unroll
      for (int i = 0; i < 16; ++i) {
        uint4 c = Cp[(r * 16 + i) * 512];
        const int k = i * 4;
        u32 a;
        a = (u32)__builtin_amdgcn_readlane((int)As0[r], k + 0); acc0 += __popc(c.x ^ a);
        a = (u32)__builtin_amdgcn_readlane((int)As0[r], k + 1); acc0 += __popc(c.y ^ a);
        a = (u32)__builtin_amdgcn_readlane((int)As0[r], k + 2); acc0 += __popc(c.z ^ a);
        a = (u32)__builtin_amdgcn_readlane((int)As0[r], k + 3); acc0 += __popc(c.w ^ a);
        a = (u32)__builtin_amdgcn_readlane((int)As1[r], k + 0); acc1 += __popc(c.x ^ a);
        a = (u32)__builtin_amdgcn_readlane((int)As1[r], k + 1); acc1 += __popc(c.y ^ a);
        a = (u32)__builtin_amdgcn_readlane((int)As1[r], k + 2); acc1 += __popc(c.z ^ a);
        a = (u32)__builtin_amdgcn_readlane((int)As1[r], k + 3); acc1 += __popc(c.w ^ a);
      }
    }
  } else {
#pragma unroll
    for (int r = 0; r < 4; ++r) {
#pragma unroll
      for (int i = 0; i < 16; ++i) {
        uint4 c = Cp[(r * 16 + i) * 512];
        const int k = i * 4;
        u32 a, z;
        a = (u32)__builtin_amdgcn_readlane((int)As0[r], k + 0);
        z = (u32)__builtin_amdgcn_readlane((int)Az0[r], k + 0); acc0 += __popc((c.x ^ a) & z);
        a = (u32)__builtin_amdgcn_readlane((int)As0[r], k + 1);
        z = (u32)__builtin_amdgcn_readlane((int)Az0[r], k + 1); acc0 += __popc((c.y ^ a) & z);
        a = (u32)__builtin_amdgcn_readlane((int)As0[r], k + 2);
        z = (u32)__builtin_amdgcn_readlane((int)Az0[r], k + 2); acc0 += __popc((c.z ^ a) & z);
        a = (u32)__builtin_amdgcn_readlane((int)As0[r], k + 3);
        z = (u32)__builtin_amdgcn_readlane((int)Az0[r], k + 3); acc0 += __popc((c.w ^ a) & z);
        a = (u32)__builtin_amdgcn_readlane((int)As1[r], k + 0);
        z = (u32)__builtin_amdgcn_readlane((int)Az1[r], k + 0); acc1 += __popc((c.x ^ a) & z);
        a = (u32)__builtin_amdgcn_readlane((int)As1[r], k + 1);
        z = (u32)__builtin_amdgcn_readlane((int)Az1[r], k + 1); acc1 += __popc((c.y ^ a) & z);
        a = (u32)__builtin_amdgcn_readlane((int)As1[r], k + 2);
        z = (u32)__builtin_amdgcn_readlane((int)Az1[r], k + 2); acc1 += __popc((c.z ^ a) & z);
        a = (u32)__builtin_amdgcn_readlane((int)As1[r], k + 3);
        z = (u32)__builtin_amdgcn_readlane((int)Az1[r], k + 3); acc1 += __popc((c.w ^ a) & z);
      }
    }
  }
  const int v = vg * 64 + lane;
  sim[(f * B + b0) * V + v] = nzc0 - 2 * acc0;
  sim[(f * B + b0 + 1) * V + v] = nzc1 - 2 * acc1;
}

// ---------------------------------------------------------------------------
// kernel B: est' = sign(sim . C) with exact 256*h + l bf16 split (unchanged
// MFMA core), int sim input, ballot-packed sign/zero bit output + conv flag.
// grid (64 dtiles, 3 f) x 256 threads. Warp w owns d-word W = blockIdx.x*4+w.
// ---------------------------------------------------------------------------
__global__ __launch_bounds__(256) void k_upd(const int* __restrict__ simBase,
                                             const bf16_t* __restrict__ CbT,
                                             u32* __restrict__ es0, u32* __restrict__ ez0,
                                             u32* __restrict__ es1, u32* __restrict__ ez1,
                                             int* __restrict__ anydiff,
                                             int* __restrict__ hzp, int iter) {
  const int f = blockIdx.y;
  const int d0 = blockIdx.x * 128;
  for (int i = 0; i < iter; ++i)
    if (anydiff[i] == 0) return;
  const u32* esIn = (iter & 1) ? es1 : es0;
  const u32* ezIn = (iter & 1) ? ez1 : ez0;
  u32* esOut = (iter & 1) ? es0 : es1;
  u32* ezOut = (iter & 1) ? ez0 : ez1;
  const int* sim = simBase + iter * (F * B * V) + f * (B * V);

  __shared__ __attribute__((aligned(16))) bf16_t lAh[64 * 88];   // [b][v]
  __shared__ __attribute__((aligned(16))) bf16_t lAl[64 * 88];   // [b][v]
  __shared__ __attribute__((aligned(16))) bf16_t lB[128 * 88];   // [d][v]

  const int t = threadIdx.x;
  const int lane = t & 63, w = t >> 6;
  const int lm = lane & 15, quad = lane >> 4;

  f32x4 zero = {0.f, 0.f, 0.f, 0.f};
  f32x4 accH[4][2], accL[4][2];
#pragma unroll
  for (int mt = 0; mt < 4; ++mt)
#pragma unroll
    for (int nt = 0; nt < 2; ++nt) { accH[mt][nt] = zero; accL[mt][nt] = zero; }

  for (int c = 0; c < 8; ++c) {
    const int vb = c * 64;
    __syncthreads();
#pragma unroll
    for (int p = 0; p < 2; ++p) {
      int q = t + 256 * p;
      int b = q >> 3, vv = (q & 7) * 8;
      const int* sp = sim + b * V + vb + vv;
#pragma unroll
      for (int i = 0; i < 8; ++i) {
        int si = sp[i];
        lAh[b * 88 + vv + i] = (bf16_t)(float)(si >> 8);
        lAl[b * 88 + vv + i] = (bf16_t)(float)(si & 255);
      }
    }
#pragma unroll
    for (int p = 0; p < 4; ++p) {
      int q = t + 256 * p;
      int r = q >> 3, vv = (q & 7) * 8;
      *(bf16x8*)&lB[r * 88 + vv] =
          *(const bf16x8*)(CbT + ((long)f * D + d0 + r) * V + vb + vv);
    }
    __syncthreads();
#pragma unroll
    for (int ks2 = 0; ks2 < 2; ++ks2) {
      const int kb = ks2 * 32 + quad * 8;
      bf16x8 bf0 = *(const bf16x8*)&lB[(w * 32 + lm) * 88 + kb];
      bf16x8 bf1 = *(const bf16x8*)&lB[(w * 32 + 16 + lm) * 88 + kb];
#pragma unroll
      for (int mt = 0; mt < 4; ++mt) {
        bf16x8 ah = *(const bf16x8*)&lAh[(mt * 16 + lm) * 88 + kb];
        bf16x8 al = *(const bf16x8*)&lAl[(mt * 16 + lm) * 88 + kb];
        accH[mt][0] = __builtin_amdgcn_mfma_f32_16x16x32_bf16(ah, bf0, accH[mt][0], 0, 0, 0);
        accH[mt][1] = __builtin_amdgcn_mfma_f32_16x16x32_bf16(ah, bf1, accH[mt][1], 0, 0, 0);
        accL[mt][0] = __builtin_amdgcn_mfma_f32_16x16x32_bf16(al, bf0, accL[mt][0], 0, 0, 0);
        accL[mt][1] = __builtin_amdgcn_mfma_f32_16x16x32_bf16(al, bf1, accL[mt][1], 0, 0, 0);
      }
    }
  }
  // epilogue: val(b, d=d0+w*32+nt*16+lm) for b = mt*16+quad*4+r.
  // ballot bit (quad*16+lm) of pass nt -> bit (nt*16+lm) of d-word W for b(quad).
  const int W = blockIdx.x * 4 + w;
  bool anyd = false, zf = false;
#pragma unroll
  for (int mt = 0; mt < 4; ++mt)
#pragma unroll
    for (int r = 0; r < 4; ++r) {
      float v0 = 256.f * accH[mt][0][r] + accL[mt][0][r];
      float v1 = 256.f * accH[mt][1][r] + accL[mt][1][r];
      u64 s0 = __ballot(v0 < 0.f);
      u64 s1 = __ballot(v1 < 0.f);
      u64 z0 = __ballot(v0 == 0.f);
      u64 z1 = __ballot(v1 == 0.f);
      zf |= ((z0 | z1) != 0ull);
      if (lm == 0) {
        u32 ws = (u32)((s0 >> (quad * 16)) & 0xffffull) |
                 (((u32)((s1 >> (quad * 16)) & 0xffffull)) << 16);
        u32 wz = (u32)((z0 >> (quad * 16)) & 0xffffull) |
                 (((u32)((z1 >> (quad * 16)) & 0xffffull)) << 16);
        int b = mt * 16 + quad * 4 + r;
        int idx = (b * F + f) * DW + W;
        esOut[idx] = ws;
        ezOut[idx] = wz;
        anyd |= (esIn[idx] != ws) || (ezIn[idx] != wz);
      }
    }
  if (__any(anyd) && lane == 0) atomicOr(&anydiff[iter], 1);
  if (zf && lane == 0) atomicOr(hzp, 1);
}

// ---------------------------------------------------------------------------
// final: argmax over V per (b,f) (first-max tie-break) + iteration count
// ---------------------------------------------------------------------------
__global__ __launch_bounds__(64) void k_out(const int* __restrict__ simBase,
                                            const int* __restrict__ anydiff,
                                            int* __restrict__ out) {
  const int* sim = simBase + ITERS * (F * B * V);
  int bid = blockIdx.x;  // 0..191
  int b = bid / F, f = bid % F;
  int lane = threadIdx.x;
  const int* row = sim + (f * B + b) * V;
  int best = -2147483647;
  int bidx = 0;
#pragma unroll
  for (int i = 0; i < V / 64; ++i) {
    int v = lane + 64 * i;  // ascending within lane -> strict > keeps first max
    int x = row[v];
    if (x > best) { best = x; bidx = v; }
  }
  for (int off = 32; off; off >>= 1) {
    int ov = __shfl_down(best, off, 64);
    int oi = __shfl_down(bidx, off, 64);
    if (ov > best || (ov == best && oi < bidx)) { best = ov; bidx = oi; }
  }
  if (lane == 0) out[b * F + f] = bidx;
  if (bid == 0 && lane == 0) {
    int first0 = ITERS;
    for (int i = 0; i < ITERS; ++i) {
      if (anydiff[i] == 0) { first0 = i; break; }
    }
    int cnt = (first0 < ITERS) ? (first0 + 1) : ITERS;
    out[B * F] = cnt - 1;
  }
}

// ---------------------------------------------------------------------------
extern "C" void kernel_launch(void* const* d_in, const int* in_sizes, int n_in,
                              void* d_out, int out_size, void* d_ws, size_t ws_size,
                              hipStream_t stream) {
  const float* inputs    = (const float*)d_in[0];  // (B, D)
  const float* init_est  = (const float*)d_in[1];  // (B, F, D)
  const float* codebooks = (const float*)d_in[2];  // (F, V, D)

  char* w = (char*)d_ws;
  size_t o = 0;
  auto alloc = [&](size_t bytes) -> void* {
    void* p = w + o;
    o = (o + bytes + 255) & ~(size_t)255;
    return p;
  };
  bf16_t* CbT  = (bf16_t*)alloc((size_t)F * D * V * 2);
  u32* Cbits   = (u32*)alloc((size_t)F * 64 * 512 * 4 * 4);  // 1.57 MB sign bits
  u32* in_bits = (u32*)alloc((size_t)B * DW * 4);
  u32* es0     = (u32*)alloc((size_t)B * F * DW * 4);
  u32* ez0     = (u32*)alloc((size_t)B * F * DW * 4);
  u32* es1     = (u32*)alloc((size_t)B * F * DW * 4);
  u32* ez1     = (u32*)alloc((size_t)B * F * DW * 4);
  int* simBase = (int*)alloc((size_t)(ITERS + 1) * F * B * V * 4);
  int* flags   = (int*)alloc(128);
  int* anydiff = flags;
  int* hz      = flags + 16;

  k_init_tr<<<dim3(128, 8, 3), 256, 0, stream>>>(codebooks, CbT, Cbits);
  k_init_pack<<<1024, 256, 0, stream>>>(inputs, init_est, in_bits, es0, ez0, flags);

  for (int j = 0; j < ITERS; ++j) {
    k_sim<<<192, 256, 0, stream>>>(Cbits, in_bits, es0, ez0, es1, ez1, simBase, anydiff, hz, j);
    k_upd<<<dim3(64, 3), 256, 0, stream>>>(simBase, CbT, es0, ez0, es1, ez1, anydiff, hz, j);
  }
  k_sim<<<192, 256, 0, stream>>>(Cbits, in_bits, es0, ez0, es1, ez1, simBase, anydiff, hz, ITERS);
  k_out<<<B * F, 64, 0, stream>>>(simBase, anydiff, (int*)d_out);
}